// Round 6
// baseline (1096.223 us; speedup 1.0000x reference)
//
#include <hip/hip_runtime.h>
#include <hip/hip_fp16.h>
#include <math.h>

#define IN_DIM   128
#define OUT_DIM  128
#define D_TIME   64
#define NSRC     50000
#define NDST     50000
#define NE       800000
#define NPB      40         // nodes per transform block (1250 blocks)
#define GR       4          // nodes per sync round
#define NR       (NPB/GR)   // 10 rounds
#define DPB      16         // dst nodes per dots block (3125 blocks)
#define EPB      256        // edges per block in k_edge
#define SLOTS    64         // max degree slots per dst (Poisson(16): P(>=64)~1e-19)
#define INV_SCALE 0.05590169943749474f  // 1/sqrt(2*128+64)

// v_d[k] = sum_j W_dst[j][k]*attn[128+j]
__global__ __launch_bounds__(256) void k_prevec(const float* __restrict__ Wd,
                                                const float* __restrict__ attn,
                                                float* __restrict__ v_d){
    int wv = threadIdx.x >> 6, lane = threadIdx.x & 63;
    int k = blockIdx.x * 4 + wv;           // 0..127
    int j = 2 * lane;
    float acc = Wd[(size_t)j*IN_DIM + k] * attn[OUT_DIM + j]
              + Wd[(size_t)(j+1)*IN_DIM + k] * attn[OUT_DIM + j + 1];
    #pragma unroll
    for (int off = 32; off > 0; off >>= 1) acc += __shfl_down(acc, off, 64);
    if (lane == 0) v_d[k] = acc;
}

// Fused front end, one grid:
//   blocks [0, 1250): transform. Register-blocked GEMV: thread (r4,kh8) owns
//     4 output rows x 16-K-chunk (64 W floats in VGPR). Reading h once per
//     4 rows cuts LDS broadcast amplification 4x vs the 1-row version
//     (16KB/node/block instead of 64KB — the measured ~60us LDS wall).
//     j4 read order rotated by kh8 so the 8 kh8 groups alias banks at most
//     2-way (free, m136). K-combine = 3 shfl_xor; s_src reduce = 3 shfl_xor.
//     Emits Zh (fp16) and s_src[node] = Z.a_s. Pure fp32 arithmetic.
//   blocks [1250, 1250+3125): s_dst dots (16 nodes/block) + counts zeroing.
__global__ __launch_bounds__(256, 4) void k_front(const float* __restrict__ h_src,
                                                  const float* __restrict__ h_dst,
                                                  const float* __restrict__ W,
                                                  const float* __restrict__ attn,
                                                  const float* __restrict__ v_d,
                                                  __half* __restrict__ Zh,
                                                  float* __restrict__ s_src,
                                                  float* __restrict__ s_dst,
                                                  int* __restrict__ counts){
    int t = threadIdx.x;
    if (blockIdx.x < NSRC/NPB){
        __shared__ float hbuf[2][GR][IN_DIM];
        __shared__ float sred[2][4][GR];
        int r4  = t >> 3;                  // row group 0..31 (rows 4*r4 .. +3)
        int kh8 = t & 7;                   // K chunk 0..7 (16 floats each)
        int wv = t >> 6, lane = t & 63;
        float4 av = ((const float4*)attn)[r4];   // a_s rows 4r4..4r4+3
        float4 wreg[4][4];                 // [row][j4] over 16-K chunk = 64 VGPR
        #pragma unroll
        for (int i = 0; i < 4; ++i){
            const float4* wp = (const float4*)(W + (size_t)(4*r4+i)*IN_DIM + kh8*16);
            #pragma unroll
            for (int j = 0; j < 4; ++j) wreg[i][j] = wp[j];
        }
        int base = blockIdx.x * NPB;
        ((float2*)hbuf[0][wv])[lane] =
            ((const float2*)(h_src + (size_t)(base + wv)*IN_DIM))[lane];
        for (int rnd = 0; rnd < NR; ++rnd){
            __syncthreads();
            if (rnd + 1 < NR)
                ((float2*)hbuf[(rnd+1)&1][wv])[lane] =
                    ((const float2*)(h_src + (size_t)(base + (rnd+1)*GR + wv)*IN_DIM))[lane];
            if (rnd > 0 && t < GR){
                int pb = (rnd-1)&1;
                s_src[base + (rnd-1)*GR + t] =
                    sred[pb][0][t]+sred[pb][1][t]+sred[pb][2][t]+sred[pb][3][t];
            }
            #pragma unroll
            for (int g = 0; g < GR; ++g){
                const float4* hc = (const float4*)(hbuf[rnd&1][g] + kh8*16);
                float acc0=0.f, acc1=0.f, acc2=0.f, acc3=0.f;
                #pragma unroll
                for (int jj = 0; jj < 4; ++jj){
                    int j4 = (jj + kh8) & 3;           // bank-rotation
                    float4 x  = hc[j4];
                    float4 w0 = wreg[0][j4], w1 = wreg[1][j4];
                    float4 w2 = wreg[2][j4], w3 = wreg[3][j4];
                    acc0 += x.x*w0.x + x.y*w0.y + x.z*w0.z + x.w*w0.w;
                    acc1 += x.x*w1.x + x.y*w1.y + x.z*w1.z + x.w*w1.w;
                    acc2 += x.x*w2.x + x.y*w2.y + x.z*w2.z + x.w*w2.w;
                    acc3 += x.x*w3.x + x.y*w3.y + x.z*w3.z + x.w*w3.w;
                }
                // K-combine across the 8 kh8 lanes (tid bits 0-2)
                #pragma unroll
                for (int off = 1; off <= 4; off <<= 1){
                    acc0 += __shfl_xor(acc0, off, 64);
                    acc1 += __shfl_xor(acc1, off, 64);
                    acc2 += __shfl_xor(acc2, off, 64);
                    acc3 += __shfl_xor(acc3, off, 64);
                }
                if (kh8 == 0){
                    union { uint2 u; __half2 h[2]; } pk;
                    pk.h[0] = __floats2half2_rn(acc0, acc1);
                    pk.h[1] = __floats2half2_rn(acc2, acc3);
                    ((uint2*)(Zh + (size_t)(base+rnd*GR+g)*OUT_DIM))[r4] = pk.u;
                }
                // s_src partial: c duplicated across kh8; reduce over r4 bits (3-5)
                float c = acc0*av.x + acc1*av.y + acc2*av.z + acc3*av.w;
                c += __shfl_xor(c, 8, 64);
                c += __shfl_xor(c, 16, 64);
                c += __shfl_xor(c, 32, 64);
                if (lane == 0) sred[rnd&1][wv][g] = c;
            }
        }
        __syncthreads();
        if (t < GR){
            int pb = (NR-1)&1;
            s_src[base + (NR-1)*GR + t] =
                sred[pb][0][t]+sred[pb][1][t]+sred[pb][2][t]+sred[pb][3][t];
        }
    } else {
        // ---- dst dots: 16 nodes/block, 4 waves x 4 sequential nodes ----
        int b = blockIdx.x - NSRC/NPB;   // 0..3124
        int wv = t >> 6, lane = t & 63;
        float2 vv = ((const float2*)v_d)[lane];   // L1-broadcast, tiny
        int n0 = b * DPB + wv;
        float2 u[4];
        #pragma unroll
        for (int it = 0; it < 4; ++it)
            u[it] = ((const float2*)(h_dst + (size_t)(n0 + it*4)*IN_DIM))[lane];
        #pragma unroll
        for (int it = 0; it < 4; ++it){
            float acc = u[it].x*vv.x + u[it].y*vv.y;
            #pragma unroll
            for (int off = 32; off > 0; off >>= 1) acc += __shfl_down(acc, off, 64);
            if (lane == 0){
                s_dst[n0 + it*4] = acc;
                counts[n0 + it*4] = 0;   // replaces hipMemsetAsync
            }
        }
    }
}

// Fused score + slot, 256 edges/block: phi . a_t (16 lanes/edge, 8-deep float4
// prefetch) -> LDS -> per-edge compose + leaky + bucket.
__global__ __launch_bounds__(256) void k_edge(const float* __restrict__ phi,
                                              const float* __restrict__ attn,
                                              const int* __restrict__ ei,
                                              const float* __restrict__ s_src,
                                              const float* __restrict__ s_dst,
                                              int2* __restrict__ slots,
                                              int* __restrict__ counts){
    __shared__ float at[D_TIME];
    __shared__ float pts[EPB];
    int t = threadIdx.x;
    if (t < D_TIME) at[t] = attn[2*OUT_DIM + t];
    __syncthreads();
    int sub = t & 15, g = t >> 4;           // 16 groups of 16 lanes
    int e0 = blockIdx.x * EPB + g;
    float a0 = at[sub*4+0], a1 = at[sub*4+1], a2 = at[sub*4+2], a3 = at[sub*4+3];
    #pragma unroll
    for (int pp = 0; pp < 16; pp += 8){
        float4 w[8];
        #pragma unroll
        for (int q = 0; q < 8; ++q)
            w[q] = ((const float4*)(phi + (size_t)(e0 + (pp+q)*16) * D_TIME))[sub];
        #pragma unroll
        for (int q = 0; q < 8; ++q){
            float acc = w[q].x*a0 + w[q].y*a1 + w[q].z*a2 + w[q].w*a3;
            #pragma unroll
            for (int off = 8; off > 0; off >>= 1) acc += __shfl_xor(acc, off, 64);
            if (sub == 0) pts[g + (pp+q)*16] = acc;
        }
    }
    __syncthreads();
    int e = blockIdx.x * EPB + t;
    int src = ei[e], dst = ei[NE + e];
    float v = s_src[src] + s_dst[dst] + pts[t];
    v = (v > 0.f) ? v : 0.2f * v;
    v *= INV_SCALE;
    int k = atomicAdd(&counts[dst], 1);
    if (k < SLOTS) slots[(dst << 6) + k] = make_int2(src, __float_as_int(v));
}

// per-dst softmax + weighted fp16-Z accumulation. One wave per dst, 4 dst/block.
// Gathers issued BEFORE softmax (indices independent of alpha) to hide L2/LLC
// latency. Half-wave per row: 32 lanes x 8B = one 256B row -> 2 rows/instr.
__global__ __launch_bounds__(256) void k_agg(const int* __restrict__ counts,
                                             const int2* __restrict__ slots,
                                             const __half* __restrict__ Zh,
                                             float* __restrict__ out){
    int wv = threadIdx.x >> 6, lane = threadIdx.x & 63;
    int half = lane >> 5, sl = lane & 31;
    int d = blockIdx.x * 4 + wv;
    int cnt = counts[d]; cnt = (cnt > SLOTS) ? SLOTS : cnt;
    float e = -1e30f; int src = 0;
    if (lane < cnt){
        int2 s = slots[(d << 6) + lane];
        src = s.x; e = __int_as_float(s.y);
    }
    int sidx[8];
    #pragma unroll
    for (int q = 0; q < 8; ++q) sidx[q] = __shfl(src, 2*q + half, 64);
    float2 raw[8];
    #pragma unroll
    for (int q = 0; q < 8; ++q)
        raw[q] = ((const float2*)(Zh + (size_t)sidx[q] * OUT_DIM))[sl];
    float m = e;
    #pragma unroll
    for (int off = 32; off > 0; off >>= 1) m = fmaxf(m, __shfl_xor(m, off, 64));
    float ex = (lane < cnt) ? __expf(e - m) : 0.f;
    float sum = ex;
    #pragma unroll
    for (int off = 32; off > 0; off >>= 1) sum += __shfl_xor(sum, off, 64);
    float alpha = ex / (sum + 1e-12f);   // lanes >= cnt: exactly 0
    float4 acc4 = make_float4(0.f, 0.f, 0.f, 0.f);
    #pragma unroll
    for (int q = 0; q < 8; ++q){
        float a = __shfl(alpha, 2*q + half, 64);
        __half2 h0 = *(__half2*)&raw[q].x;
        __half2 h1 = *(__half2*)&raw[q].y;
        float2 f0 = __half22float2(h0);
        float2 f1 = __half22float2(h1);
        acc4.x += a*f0.x; acc4.y += a*f0.y;
        acc4.z += a*f1.x; acc4.w += a*f1.y;
    }
    int jmax = (cnt + 15) & ~15;
    for (int j = 16; j < jmax; j += 16){
        float a[8]; int s[8];
        #pragma unroll
        for (int q = 0; q < 8; ++q){
            int idx = j + 2*q + half;
            a[q] = __shfl(alpha, idx, 64);
            s[q] = __shfl(src,   idx, 64);
        }
        float2 r2[8];
        #pragma unroll
        for (int q = 0; q < 8; ++q)
            r2[q] = ((const float2*)(Zh + (size_t)s[q] * OUT_DIM))[sl];
        #pragma unroll
        for (int q = 0; q < 8; ++q){
            __half2 h0 = *(__half2*)&r2[q].x;
            __half2 h1 = *(__half2*)&r2[q].y;
            float2 f0 = __half22float2(h0);
            float2 f1 = __half22float2(h1);
            acc4.x += a[q]*f0.x; acc4.y += a[q]*f0.y;
            acc4.z += a[q]*f1.x; acc4.w += a[q]*f1.y;
        }
    }
    acc4.x += __shfl_xor(acc4.x, 32, 64);
    acc4.y += __shfl_xor(acc4.y, 32, 64);
    acc4.z += __shfl_xor(acc4.z, 32, 64);
    acc4.w += __shfl_xor(acc4.w, 32, 64);
    if (!half) ((float4*)(out + (size_t)d * OUT_DIM))[sl] = acc4;
}

extern "C" void kernel_launch(void* const* d_in, const int* in_sizes, int n_in,
                              void* d_out, int out_size, void* d_ws, size_t ws_size,
                              hipStream_t stream){
    const float* h_src = (const float*)d_in[0];
    const float* h_dst = (const float*)d_in[1];
    const int*   ei    = (const int*)d_in[2];
    const float* phi   = (const float*)d_in[3];
    const float* Wsrc  = (const float*)d_in[4];
    const float* Wdst  = (const float*)d_in[5];
    const float* attn  = (const float*)d_in[6];
    float* out = (float*)d_out;

    char* p = (char*)d_ws;
    auto alloc = [&](size_t bytes)->char*{
        char* r = p; p += (bytes + 255) / 256 * 256; return r;
    };
    __half* Zh   = (__half*)alloc((size_t)NSRC*OUT_DIM*2);
    float* s_src = (float*)alloc((size_t)NSRC*4);
    float* s_dst = (float*)alloc((size_t)NDST*4);
    float* v_d   = (float*)alloc(128*4);
    int2*  slots = (int2*)alloc((size_t)NDST*SLOTS*8);
    int*   counts= (int*)alloc((size_t)NDST*4);

    k_prevec<<<32, 256, 0, stream>>>(Wdst, attn, v_d);
    k_front<<<NSRC/NPB + NDST/DPB, 256, 0, stream>>>(
        h_src, h_dst, Wsrc, attn, v_d, Zh, s_src, s_dst, counts);
    k_edge<<<NE/EPB, 256, 0, stream>>>(phi, attn, ei, s_src, s_dst, slots, counts);
    k_agg<<<NDST/4, 256, 0, stream>>>(counts, slots, Zh, out);
}

// Round 7
// 425.256 us; speedup vs baseline: 2.5778x; 2.5778x over previous
//
#include <hip/hip_runtime.h>
#include <hip/hip_fp16.h>
#include <math.h>

#define IN_DIM   128
#define OUT_DIM  128
#define D_TIME   64
#define NSRC     50000
#define NDST     50000
#define NE       800000
#define NPB      40         // nodes per transform block (1250 blocks)
#define GR       4          // nodes per sync round
#define NR       (NPB/GR)   // 10 rounds
#define DPB      16         // dst nodes per dots block (3125 blocks)
#define EPB      256        // edges per block in k_edge
#define SLOTS    64         // max degree slots per dst (Poisson(16): P(>=64)~1e-19)
#define INV_SCALE 0.05590169943749474f  // 1/sqrt(2*128+64)

// v_d[k] = sum_j W_dst[j][k]*attn[128+j]
__global__ __launch_bounds__(256) void k_prevec(const float* __restrict__ Wd,
                                                const float* __restrict__ attn,
                                                float* __restrict__ v_d){
    int wv = threadIdx.x >> 6, lane = threadIdx.x & 63;
    int k = blockIdx.x * 4 + wv;           // 0..127
    int j = 2 * lane;
    float acc = Wd[(size_t)j*IN_DIM + k] * attn[OUT_DIM + j]
              + Wd[(size_t)(j+1)*IN_DIM + k] * attn[OUT_DIM + j + 1];
    #pragma unroll
    for (int off = 32; off > 0; off >>= 1) acc += __shfl_down(acc, off, 64);
    if (lane == 0) v_d[k] = acc;
}

// Fused front end, one grid:
//   blocks [0, 1250): transform. Register-blocked GEMV: thread (r4,kh8) owns
//     4 output rows x 16-K-chunk (64 W floats in VGPR). h read once per 4 rows
//     -> 16KB LDS traffic/node/block (4x less than 1-row version).
//     Bank spread: W chunks are PRE-ROTATED AT LOAD TIME (wreg[i][jj] holds
//     chunk (jj+rot)&3), so the hot loop indexes wreg with COMPILE-TIME jj
//     (rule #20: runtime reg-array index -> scratch; that was round 6's 770us
//     disaster, VGPR=52 / FETCH=1.4GB) while the LDS read address rotates
//     (runtime addr is fine). 2-way bank alias max = free (m136).
//     Emits Zh (fp16) and s_src[node] = Z.a_s. Pure fp32 arithmetic.
//   blocks [1250, 1250+3125): s_dst dots (16 nodes/block) + counts zeroing.
__global__ __launch_bounds__(256, 4) void k_front(const float* __restrict__ h_src,
                                                  const float* __restrict__ h_dst,
                                                  const float* __restrict__ W,
                                                  const float* __restrict__ attn,
                                                  const float* __restrict__ v_d,
                                                  __half* __restrict__ Zh,
                                                  float* __restrict__ s_src,
                                                  float* __restrict__ s_dst,
                                                  int* __restrict__ counts){
    int t = threadIdx.x;
    if (blockIdx.x < NSRC/NPB){
        __shared__ float hbuf[2][GR][IN_DIM];
        __shared__ float sred[2][4][GR];
        int r4  = t >> 3;                  // row group 0..31 (rows 4*r4 .. +3)
        int kh8 = t & 7;                   // K chunk 0..7 (16 floats each)
        int rot = kh8 & 3;                 // bank-rotation amount
        int wv = t >> 6, lane = t & 63;
        float4 av = ((const float4*)attn)[r4];   // a_s rows 4r4..4r4+3
        // wreg[i][jj] = W row 4r4+i, K-chunk (jj+rot)&3 of this thread's region.
        // Rotation folded into the GLOBAL LOAD so hot-loop reg indices are
        // compile-time constants.
        float4 wreg[4][4];
        #pragma unroll
        for (int i = 0; i < 4; ++i){
            const float4* wp = (const float4*)(W + (size_t)(4*r4+i)*IN_DIM + kh8*16);
            #pragma unroll
            for (int jj = 0; jj < 4; ++jj) wreg[i][jj] = wp[(jj + rot) & 3];
        }
        int base = blockIdx.x * NPB;
        ((float2*)hbuf[0][wv])[lane] =
            ((const float2*)(h_src + (size_t)(base + wv)*IN_DIM))[lane];
        for (int rnd = 0; rnd < NR; ++rnd){
            __syncthreads();
            if (rnd + 1 < NR)
                ((float2*)hbuf[(rnd+1)&1][wv])[lane] =
                    ((const float2*)(h_src + (size_t)(base + (rnd+1)*GR + wv)*IN_DIM))[lane];
            if (rnd > 0 && t < GR){
                int pb = (rnd-1)&1;
                s_src[base + (rnd-1)*GR + t] =
                    sred[pb][0][t]+sred[pb][1][t]+sred[pb][2][t]+sred[pb][3][t];
            }
            #pragma unroll
            for (int g = 0; g < GR; ++g){
                const float4* hc = (const float4*)(hbuf[rnd&1][g] + kh8*16);
                float acc0=0.f, acc1=0.f, acc2=0.f, acc3=0.f;
                #pragma unroll
                for (int jj = 0; jj < 4; ++jj){
                    float4 x  = hc[(jj + rot) & 3];        // runtime LDS addr: ok
                    float4 w0 = wreg[0][jj], w1 = wreg[1][jj];   // compile-time
                    float4 w2 = wreg[2][jj], w3 = wreg[3][jj];
                    acc0 += x.x*w0.x + x.y*w0.y + x.z*w0.z + x.w*w0.w;
                    acc1 += x.x*w1.x + x.y*w1.y + x.z*w1.z + x.w*w1.w;
                    acc2 += x.x*w2.x + x.y*w2.y + x.z*w2.z + x.w*w2.w;
                    acc3 += x.x*w3.x + x.y*w3.y + x.z*w3.z + x.w*w3.w;
                }
                // K-combine across the 8 kh8 lanes (tid bits 0-2)
                #pragma unroll
                for (int off = 1; off <= 4; off <<= 1){
                    acc0 += __shfl_xor(acc0, off, 64);
                    acc1 += __shfl_xor(acc1, off, 64);
                    acc2 += __shfl_xor(acc2, off, 64);
                    acc3 += __shfl_xor(acc3, off, 64);
                }
                if (kh8 == 0){
                    union { uint2 u; __half2 h[2]; } pk;
                    pk.h[0] = __floats2half2_rn(acc0, acc1);
                    pk.h[1] = __floats2half2_rn(acc2, acc3);
                    ((uint2*)(Zh + (size_t)(base+rnd*GR+g)*OUT_DIM))[r4] = pk.u;
                }
                // s_src partial: c duplicated across kh8; reduce over r4 bits (3-5)
                float c = acc0*av.x + acc1*av.y + acc2*av.z + acc3*av.w;
                c += __shfl_xor(c, 8, 64);
                c += __shfl_xor(c, 16, 64);
                c += __shfl_xor(c, 32, 64);
                if (lane == 0) sred[rnd&1][wv][g] = c;
            }
        }
        __syncthreads();
        if (t < GR){
            int pb = (NR-1)&1;
            s_src[base + (NR-1)*GR + t] =
                sred[pb][0][t]+sred[pb][1][t]+sred[pb][2][t]+sred[pb][3][t];
        }
    } else {
        // ---- dst dots: 16 nodes/block, 4 waves x 4 sequential nodes ----
        int b = blockIdx.x - NSRC/NPB;   // 0..3124
        int wv = t >> 6, lane = t & 63;
        float2 vv = ((const float2*)v_d)[lane];   // L1-broadcast, tiny
        int n0 = b * DPB + wv;
        float2 u[4];
        #pragma unroll
        for (int it = 0; it < 4; ++it)
            u[it] = ((const float2*)(h_dst + (size_t)(n0 + it*4)*IN_DIM))[lane];
        #pragma unroll
        for (int it = 0; it < 4; ++it){
            float acc = u[it].x*vv.x + u[it].y*vv.y;
            #pragma unroll
            for (int off = 32; off > 0; off >>= 1) acc += __shfl_down(acc, off, 64);
            if (lane == 0){
                s_dst[n0 + it*4] = acc;
                counts[n0 + it*4] = 0;   // replaces hipMemsetAsync
            }
        }
    }
}

// Fused score + slot, 256 edges/block: phi . a_t (16 lanes/edge, 8-deep float4
// prefetch) -> LDS -> per-edge compose + leaky + bucket.
__global__ __launch_bounds__(256) void k_edge(const float* __restrict__ phi,
                                              const float* __restrict__ attn,
                                              const int* __restrict__ ei,
                                              const float* __restrict__ s_src,
                                              const float* __restrict__ s_dst,
                                              int2* __restrict__ slots,
                                              int* __restrict__ counts){
    __shared__ float at[D_TIME];
    __shared__ float pts[EPB];
    int t = threadIdx.x;
    if (t < D_TIME) at[t] = attn[2*OUT_DIM + t];
    __syncthreads();
    int sub = t & 15, g = t >> 4;           // 16 groups of 16 lanes
    int e0 = blockIdx.x * EPB + g;
    float a0 = at[sub*4+0], a1 = at[sub*4+1], a2 = at[sub*4+2], a3 = at[sub*4+3];
    #pragma unroll
    for (int pp = 0; pp < 16; pp += 8){
        float4 w[8];
        #pragma unroll
        for (int q = 0; q < 8; ++q)
            w[q] = ((const float4*)(phi + (size_t)(e0 + (pp+q)*16) * D_TIME))[sub];
        #pragma unroll
        for (int q = 0; q < 8; ++q){
            float acc = w[q].x*a0 + w[q].y*a1 + w[q].z*a2 + w[q].w*a3;
            #pragma unroll
            for (int off = 8; off > 0; off >>= 1) acc += __shfl_xor(acc, off, 64);
            if (sub == 0) pts[g + (pp+q)*16] = acc;
        }
    }
    __syncthreads();
    int e = blockIdx.x * EPB + t;
    int src = ei[e], dst = ei[NE + e];
    float v = s_src[src] + s_dst[dst] + pts[t];
    v = (v > 0.f) ? v : 0.2f * v;
    v *= INV_SCALE;
    int k = atomicAdd(&counts[dst], 1);
    if (k < SLOTS) slots[(dst << 6) + k] = make_int2(src, __float_as_int(v));
}

// per-dst softmax + weighted fp16-Z accumulation. One wave per dst, 4 dst/block.
// Gathers issued BEFORE softmax (indices independent of alpha) to hide L2/LLC
// latency. Half-wave per row: 32 lanes x 8B = one 256B row -> 2 rows/instr.
__global__ __launch_bounds__(256) void k_agg(const int* __restrict__ counts,
                                             const int2* __restrict__ slots,
                                             const __half* __restrict__ Zh,
                                             float* __restrict__ out){
    int wv = threadIdx.x >> 6, lane = threadIdx.x & 63;
    int half = lane >> 5, sl = lane & 31;
    int d = blockIdx.x * 4 + wv;
    int cnt = counts[d]; cnt = (cnt > SLOTS) ? SLOTS : cnt;
    float e = -1e30f; int src = 0;
    if (lane < cnt){
        int2 s = slots[(d << 6) + lane];
        src = s.x; e = __int_as_float(s.y);
    }
    int sidx[8];
    #pragma unroll
    for (int q = 0; q < 8; ++q) sidx[q] = __shfl(src, 2*q + half, 64);
    float2 raw[8];
    #pragma unroll
    for (int q = 0; q < 8; ++q)
        raw[q] = ((const float2*)(Zh + (size_t)sidx[q] * OUT_DIM))[sl];
    float m = e;
    #pragma unroll
    for (int off = 32; off > 0; off >>= 1) m = fmaxf(m, __shfl_xor(m, off, 64));
    float ex = (lane < cnt) ? __expf(e - m) : 0.f;
    float sum = ex;
    #pragma unroll
    for (int off = 32; off > 0; off >>= 1) sum += __shfl_xor(sum, off, 64);
    float alpha = ex / (sum + 1e-12f);   // lanes >= cnt: exactly 0
    float4 acc4 = make_float4(0.f, 0.f, 0.f, 0.f);
    #pragma unroll
    for (int q = 0; q < 8; ++q){
        float a = __shfl(alpha, 2*q + half, 64);
        __half2 h0 = *(__half2*)&raw[q].x;
        __half2 h1 = *(__half2*)&raw[q].y;
        float2 f0 = __half22float2(h0);
        float2 f1 = __half22float2(h1);
        acc4.x += a*f0.x; acc4.y += a*f0.y;
        acc4.z += a*f1.x; acc4.w += a*f1.y;
    }
    int jmax = (cnt + 15) & ~15;
    for (int j = 16; j < jmax; j += 16){
        float a[8]; int s[8];
        #pragma unroll
        for (int q = 0; q < 8; ++q){
            int idx = j + 2*q + half;
            a[q] = __shfl(alpha, idx, 64);
            s[q] = __shfl(src,   idx, 64);
        }
        float2 r2[8];
        #pragma unroll
        for (int q = 0; q < 8; ++q)
            r2[q] = ((const float2*)(Zh + (size_t)s[q] * OUT_DIM))[sl];
        #pragma unroll
        for (int q = 0; q < 8; ++q){
            __half2 h0 = *(__half2*)&r2[q].x;
            __half2 h1 = *(__half2*)&r2[q].y;
            float2 f0 = __half22float2(h0);
            float2 f1 = __half22float2(h1);
            acc4.x += a[q]*f0.x; acc4.y += a[q]*f0.y;
            acc4.z += a[q]*f1.x; acc4.w += a[q]*f1.y;
        }
    }
    acc4.x += __shfl_xor(acc4.x, 32, 64);
    acc4.y += __shfl_xor(acc4.y, 32, 64);
    acc4.z += __shfl_xor(acc4.z, 32, 64);
    acc4.w += __shfl_xor(acc4.w, 32, 64);
    if (!half) ((float4*)(out + (size_t)d * OUT_DIM))[sl] = acc4;
}

extern "C" void kernel_launch(void* const* d_in, const int* in_sizes, int n_in,
                              void* d_out, int out_size, void* d_ws, size_t ws_size,
                              hipStream_t stream){
    const float* h_src = (const float*)d_in[0];
    const float* h_dst = (const float*)d_in[1];
    const int*   ei    = (const int*)d_in[2];
    const float* phi   = (const float*)d_in[3];
    const float* Wsrc  = (const float*)d_in[4];
    const float* Wdst  = (const float*)d_in[5];
    const float* attn  = (const float*)d_in[6];
    float* out = (float*)d_out;

    char* p = (char*)d_ws;
    auto alloc = [&](size_t bytes)->char*{
        char* r = p; p += (bytes + 255) / 256 * 256; return r;
    };
    __half* Zh   = (__half*)alloc((size_t)NSRC*OUT_DIM*2);
    float* s_src = (float*)alloc((size_t)NSRC*4);
    float* s_dst = (float*)alloc((size_t)NDST*4);
    float* v_d   = (float*)alloc(128*4);
    int2*  slots = (int2*)alloc((size_t)NDST*SLOTS*8);
    int*   counts= (int*)alloc((size_t)NDST*4);

    k_prevec<<<32, 256, 0, stream>>>(Wdst, attn, v_d);
    k_front<<<NSRC/NPB + NDST/DPB, 256, 0, stream>>>(
        h_src, h_dst, Wsrc, attn, v_d, Zh, s_src, s_dst, counts);
    k_edge<<<NE/EPB, 256, 0, stream>>>(phi, attn, ei, s_src, s_dst, slots, counts);
    k_agg<<<NDST/4, 256, 0, stream>>>(counts, slots, Zh, out);
}